// Round 1
// baseline (3785.160 us; speedup 1.0000x reference)
//
#include <hip/hip_runtime.h>
#include <math.h>

// ---- problem constants ----
constexpr int Bc  = 2;
constexpr int Lc  = 1024;
constexpr int BL  = Bc * Lc;    // 2048
constexpr int HS  = 2048;
constexpr int NH  = 8;
constexpr int HD  = 256;
constexpr int DV  = 512;
constexpr int KD  = NH * HD;    // 2048
constexpr int VD  = NH * DV;    // 4096
constexpr int NE  = 3;
constexpr int KSZ = 4;

__device__ __forceinline__ float sigf(float x) { return 1.f / (1.f + expf(-x)); }

// =====================================================================
// Generic fp32 GEMM  C[M,N] = A[M,K(lda)] * W[N,K(ldw)]^T  (64x64 tile)
// =====================================================================
__device__ __forceinline__ void gemm_body(const float* __restrict__ A, int lda,
                                          const float* __restrict__ W, int ldw,
                                          float* __restrict__ C, int ldc,
                                          int M, int N, int K,
                                          float* As, float* Ws) {
  const int tid = threadIdx.x;
  const int m0 = blockIdx.y * 64, n0 = blockIdx.x * 64;
  const int tx = tid & 15, ty = tid >> 4;
  const int lr = tid >> 2;          // 0..63 tile row
  const int lc = (tid & 3) << 2;    // 0,4,8,12 k-col
  float acc[4][4] = {{0.f,0.f,0.f,0.f},{0.f,0.f,0.f,0.f},{0.f,0.f,0.f,0.f},{0.f,0.f,0.f,0.f}};
  for (int k0 = 0; k0 < K; k0 += 16) {
    float4 av = make_float4(0.f,0.f,0.f,0.f), wv = make_float4(0.f,0.f,0.f,0.f);
    if (m0 + lr < M) av = *(const float4*)&A[(size_t)(m0 + lr) * lda + k0 + lc];
    if (n0 + lr < N) wv = *(const float4*)&W[(size_t)(n0 + lr) * ldw + k0 + lc];
    __syncthreads();
    As[(lc+0)*68 + lr] = av.x; As[(lc+1)*68 + lr] = av.y;
    As[(lc+2)*68 + lr] = av.z; As[(lc+3)*68 + lr] = av.w;
    Ws[(lc+0)*68 + lr] = wv.x; Ws[(lc+1)*68 + lr] = wv.y;
    Ws[(lc+2)*68 + lr] = wv.z; Ws[(lc+3)*68 + lr] = wv.w;
    __syncthreads();
#pragma unroll
    for (int kk = 0; kk < 16; kk++) {
      float4 a4 = *(const float4*)&As[kk*68 + ty*4];
      float4 w4 = *(const float4*)&Ws[kk*68 + tx*4];
      float ar[4] = {a4.x, a4.y, a4.z, a4.w};
      float wr[4] = {w4.x, w4.y, w4.z, w4.w};
#pragma unroll
      for (int i = 0; i < 4; i++)
#pragma unroll
        for (int j = 0; j < 4; j++)
          acc[i][j] = fmaf(ar[i], wr[j], acc[i][j]);
    }
  }
#pragma unroll
  for (int i = 0; i < 4; i++) {
    int m = m0 + ty*4 + i;
    if (m >= M) continue;
#pragma unroll
    for (int j = 0; j < 4; j++) {
      int n = n0 + tx*4 + j;
      if (n < N) C[(size_t)m * ldc + n] = acc[i][j];
    }
  }
}

__global__ __launch_bounds__(256) void gemm_nt_kernel(const float* __restrict__ A,
    const float* __restrict__ W, float* __restrict__ C, int M, int N, int K) {
  __shared__ float As[16*68];
  __shared__ float Ws[16*68];
  gemm_body(A, K, W, K, C, N, M, N, K, As, Ws);
}

// ke[e, t, h, :] = k[t, h, :] @ W_ek[e,h]^T   (batched over z = e*NH+h)
__global__ __launch_bounds__(256) void gemm_ke_kernel(const float* __restrict__ k,
    const float* __restrict__ wek, float* __restrict__ ke) {
  __shared__ float As[16*68];
  __shared__ float Ws[16*68];
  int z = blockIdx.z; int e = z >> 3, h = z & 7;
  const float* A = k + h * HD;                       // lda = KD
  const float* W = wek + (size_t)z * HD * HD;        // ldw = HD
  float* C = ke + (size_t)e * BL * KD + h * HD;      // ldc = KD
  gemm_body(A, KD, W, HD, C, KD, BL, HD, HD, As, Ws);
}

// =====================================================================
// causal depthwise conv (K=4) + SiLU.  x,y: [BL, C], w: [C, 4]
// =====================================================================
__global__ __launch_bounds__(256) void conv_silu_kernel(const float* __restrict__ x,
    const float* __restrict__ w, float* __restrict__ y, int C) {
  int idx = blockIdx.x * blockDim.x + threadIdx.x;
  int nc4 = C >> 2;
  if (idx >= BL * nc4) return;
  int c4 = (idx % nc4) << 2;
  int t  = idx / nc4;
  int b = t / Lc, l = t % Lc;
  float4 w0 = *(const float4*)&w[(c4+0)*KSZ];
  float4 w1 = *(const float4*)&w[(c4+1)*KSZ];
  float4 w2 = *(const float4*)&w[(c4+2)*KSZ];
  float4 w3 = *(const float4*)&w[(c4+3)*KSZ];
  const float* p0 = (const float*)&w0; const float* p1 = (const float*)&w1;
  const float* p2 = (const float*)&w2; const float* p3 = (const float*)&w3;
  float4 acc = make_float4(0.f,0.f,0.f,0.f);
#pragma unroll
  for (int i = 0; i < KSZ; i++) {
    int ls = l - (KSZ - 1) + i;
    if (ls < 0) continue;
    float4 xv = *(const float4*)&x[(size_t)(b * Lc + ls) * C + c4];
    acc.x = fmaf(xv.x, p0[i], acc.x);
    acc.y = fmaf(xv.y, p1[i], acc.y);
    acc.z = fmaf(xv.z, p2[i], acc.z);
    acc.w = fmaf(xv.w, p3[i], acc.w);
  }
  acc.x *= sigf(acc.x); acc.y *= sigf(acc.y); acc.z *= sigf(acc.z); acc.w *= sigf(acc.w);
  *(float4*)&y[(size_t)t * C + c4] = acc;
}

// =====================================================================
// l2norm over last dim (HD=256) in place, one wave per row, * scale
// =====================================================================
__global__ __launch_bounds__(256) void l2norm_kernel(float* __restrict__ q, float scale, int rows) {
  int wid = threadIdx.x >> 6, lane = threadIdx.x & 63;
  int row = (blockIdx.x << 2) + wid;
  if (row >= rows) return;
  float* p = q + (size_t)row * HD;
  float4 a = *(const float4*)&p[lane * 4];
  float ss = a.x*a.x + a.y*a.y + a.z*a.z + a.w*a.w;
#pragma unroll
  for (int off = 32; off >= 1; off >>= 1) ss += __shfl_xor(ss, off, 64);
  float r = rsqrtf(ss + 1e-6f) * scale;
  a.x *= r; a.y *= r; a.z *= r; a.w *= r;
  *(float4*)&p[lane * 4] = a;
}

// =====================================================================
// per-token gate scalars: dec = m*exp(g)+(1-m), bm = beta*m
// layouts: xb/xa [BL,24], outputs [E][B][NH][L]
// =====================================================================
__global__ __launch_bounds__(256) void scalars_kernel(const float* __restrict__ xb,
    const float* __restrict__ xa, const int* __restrict__ modality,
    const float* __restrict__ A_log, const float* __restrict__ dt_bias,
    float* __restrict__ dec, float* __restrict__ bm) {
  int idx = blockIdx.x * blockDim.x + threadIdx.x;
  if (idx >= BL * NE * NH) return;
  int eh = idx % (NE * NH);
  int t  = idx / (NE * NH);
  int e = eh / NH, h = eh % NH;
  float a    = xa[(size_t)t * (NE*NH) + eh];
  float beta = sigf(xb[(size_t)t * (NE*NH) + eh]);
  int md = modality[t];
  float m = (e == 0) ? 1.f : ((e == 1) ? (md == 0 ? 1.f : 0.f) : (md == 1 ? 1.f : 0.f));
  float spin = a + dt_bias[eh];
  float sp = (spin > 20.f) ? spin : log1pf(expf(spin));
  float g = -expf(A_log[eh]) * sp;
  float d = m * expf(g) + (1.f - m);
  int b = t / Lc, l = t % Lc;
  size_t off = ((size_t)(e * Bc + b) * NH + h) * Lc + l;
  dec[off] = d;
  bm[off]  = beta * m;
}

// softmax over E=3 per head
__global__ void wout_kernel(const float* __restrict__ ow, float* __restrict__ wout) {
  int h = threadIdx.x;
  if (h >= NH) return;
  float e0 = ow[0*NH + h], e1 = ow[1*NH + h], e2 = ow[2*NH + h];
  float mx = fmaxf(e0, fmaxf(e1, e2));
  float x0 = expf(e0 - mx), x1 = expf(e1 - mx), x2 = expf(e2 - mx);
  float s = x0 + x1 + x2;
  wout[0*NH + h] = x0 / s; wout[1*NH + h] = x1 / s; wout[2*NH + h] = x2 / s;
}

// =====================================================================
// gated delta scan. One wave per (e, b, h, 16-column chunk of DV).
// lane = p*16 + vl: column vl (of 16), k-quarter p (64 k's) in registers.
// =====================================================================
__global__ __launch_bounds__(64) void scan_kernel(
    const float* __restrict__ ke, const float* __restrict__ q,
    const float* __restrict__ v,  const float* __restrict__ dec,
    const float* __restrict__ bm, const float* __restrict__ wout,
    float* __restrict__ o) {
  const int wg = blockIdx.x;
  const int chunk = wg & 31;
  const int h = (wg >> 5) & 7;
  const int b = (wg >> 8) & 1;
  const int e = wg >> 9;
  const int lane = threadIdx.x;
  const int vl = lane & 15, p = lane >> 4;

  __shared__ float kbuf[4 * 72];
  __shared__ float qbuf[4 * 72];

  float S[64];
#pragma unroll
  for (int i = 0; i < 64; i++) S[i] = 0.f;

  const float* decp = dec + ((size_t)(e * Bc + b) * NH + h) * Lc;
  const float* bmp  = bm  + ((size_t)(e * Bc + b) * NH + h) * Lc;
  const float weh = wout[e * NH + h];
  const size_t keb = ((size_t)e * BL + (size_t)b * Lc) * KD + h * HD;
  const size_t qb0 = ((size_t)b * Lc) * KD + h * HD;
  const size_t vb0 = ((size_t)b * Lc) * VD + h * DV + chunk * 16;
  float* ob = o + (size_t)b * Lc * VD + h * DV + chunk * 16;

  for (int t = 0; t < Lc; t++) {
    float4 kv = *(const float4*)&ke[keb + (size_t)t * KD + lane * 4];
    float4 qv = *(const float4*)&q[qb0 + (size_t)t * KD + lane * 4];
    float vval = v[vb0 + (size_t)t * VD + vl];
    float dct = decp[t], bmt = bmp[t];
    __syncthreads();
    *(float4*)&kbuf[p * 72 + vl * 4] = kv;  // element 4*lane -> slice p, pos 4*vl
    *(float4*)&qbuf[p * 72 + vl * 4] = qv;
    __syncthreads();
    const float4* kp = (const float4*)&kbuf[p * 72];
    const float4* qp = (const float4*)&qbuf[p * 72];
    float4 kr[16];
#pragma unroll
    for (int i = 0; i < 16; i++) kr[i] = kp[i];
    float part = 0.f;
#pragma unroll
    for (int i = 0; i < 16; i++) {
      part += kr[i].x * S[4*i+0] + kr[i].y * S[4*i+1]
            + kr[i].z * S[4*i+2] + kr[i].w * S[4*i+3];
    }
    part += __shfl_xor(part, 16, 64);
    part += __shfl_xor(part, 32, 64);
    float pred  = dct * part;                 // k . (dec*S_old)
    float delta = (vval - pred) * bmt;
    float opart = 0.f;
#pragma unroll
    for (int i = 0; i < 16; i++) {
      float4 qq = qp[i];
      float s0 = fmaf(kr[i].x, delta, dct * S[4*i+0]); S[4*i+0] = s0; opart = fmaf(qq.x, s0, opart);
      float s1 = fmaf(kr[i].y, delta, dct * S[4*i+1]); S[4*i+1] = s1; opart = fmaf(qq.y, s1, opart);
      float s2 = fmaf(kr[i].z, delta, dct * S[4*i+2]); S[4*i+2] = s2; opart = fmaf(qq.z, s2, opart);
      float s3 = fmaf(kr[i].w, delta, dct * S[4*i+3]); S[4*i+3] = s3; opart = fmaf(qq.w, s3, opart);
    }
    opart += __shfl_xor(opart, 16, 64);
    opart += __shfl_xor(opart, 32, 64);
    if (p == 0) atomicAdd(&ob[(size_t)t * VD + vl], weh * opart);
  }
}

// =====================================================================
// RMSNorm(DV) * o_norm_weight * SiLU(gate), in place on o. one wave/row
// =====================================================================
__global__ __launch_bounds__(256) void gate_kernel(float* __restrict__ o,
    const float* __restrict__ xg, const float* __restrict__ onw) {
  int wid = threadIdx.x >> 6, lane = threadIdx.x & 63;
  int row = (blockIdx.x << 2) + wid;      // over BL*NH
  if (row >= BL * NH) return;
  int t = row >> 3, h = row & 7;
  float* op = o + (size_t)t * VD + h * DV;
  const float* gp = xg + (size_t)t * VD + h * DV;
  float4 a0 = *(const float4*)&op[lane * 8];
  float4 a1 = *(const float4*)&op[lane * 8 + 4];
  float ss = a0.x*a0.x + a0.y*a0.y + a0.z*a0.z + a0.w*a0.w
           + a1.x*a1.x + a1.y*a1.y + a1.z*a1.z + a1.w*a1.w;
#pragma unroll
  for (int off = 32; off >= 1; off >>= 1) ss += __shfl_xor(ss, off, 64);
  float r = rsqrtf(ss * (1.f / DV) + 1e-5f);
  float4 g0 = *(const float4*)&gp[lane * 8];
  float4 g1 = *(const float4*)&gp[lane * 8 + 4];
  float4 n0 = *(const float4*)&onw[lane * 8];
  float4 n1 = *(const float4*)&onw[lane * 8 + 4];
  a0.x = a0.x * r * n0.x * (g0.x * sigf(g0.x));
  a0.y = a0.y * r * n0.y * (g0.y * sigf(g0.y));
  a0.z = a0.z * r * n0.z * (g0.z * sigf(g0.z));
  a0.w = a0.w * r * n0.w * (g0.w * sigf(g0.w));
  a1.x = a1.x * r * n1.x * (g1.x * sigf(g1.x));
  a1.y = a1.y * r * n1.y * (g1.y * sigf(g1.y));
  a1.z = a1.z * r * n1.z * (g1.z * sigf(g1.z));
  a1.w = a1.w * r * n1.w * (g1.w * sigf(g1.w));
  *(float4*)&op[lane * 8]     = a0;
  *(float4*)&op[lane * 8 + 4] = a1;
}

// =====================================================================
extern "C" void kernel_launch(void* const* d_in, const int* in_sizes, int n_in,
                              void* d_out, int out_size, void* d_ws, size_t ws_size,
                              hipStream_t stream) {
  const float* x    = (const float*)d_in[0];
  const int*   modv = (const int*)d_in[1];
  const float* Wq   = (const float*)d_in[2];
  const float* Wk   = (const float*)d_in[3];
  const float* Wv   = (const float*)d_in[4];
  const float* cq   = (const float*)d_in[5];
  const float* ck   = (const float*)d_in[6];
  const float* cv   = (const float*)d_in[7];
  const float* Wek  = (const float*)d_in[8];
  const float* Wb   = (const float*)d_in[9];
  const float* Wa   = (const float*)d_in[10];
  const float* Alog = (const float*)d_in[11];
  const float* dtb  = (const float*)d_in[12];
  const float* ow   = (const float*)d_in[13];
  const float* Wg   = (const float*)d_in[14];
  const float* onw  = (const float*)d_in[15];
  const float* Wo   = (const float*)d_in[16];
  float* out = (float*)d_out;
  float* ws  = (float*)d_ws;

  const size_t M1 = 1024 * 1024;
  float* xq_raw = ws;                 // 4M
  float* xk_raw = ws + 4 * M1;        // 4M
  float* xv_raw = ws + 8 * M1;        // 8M
  float* keb    = ws;                 // 12M (reuses raw region after convs)
  float* qb     = ws + 16 * M1;       // 4M
  float* kb     = ws + 20 * M1;       // 4M
  float* vb     = ws + 24 * M1;       // 8M
  float* xgb    = ws + 32 * M1;       // 8M
  float* ob     = ws + 40 * M1;       // 8M
  float* xbb    = ws + 48 * M1;       // 48K
  float* xab    = xbb + 65536;
  float* decb   = xab + 65536;
  float* bmb    = decb + 65536;
  float* woutb  = bmb + 65536;

  dim3 blk(256);
  // projections
  gemm_nt_kernel<<<dim3(KD/64, BL/64), blk, 0, stream>>>(x, Wq, xq_raw, BL, KD, HS);
  gemm_nt_kernel<<<dim3(KD/64, BL/64), blk, 0, stream>>>(x, Wk, xk_raw, BL, KD, HS);
  gemm_nt_kernel<<<dim3(VD/64, BL/64), blk, 0, stream>>>(x, Wv, xv_raw, BL, VD, HS);
  gemm_nt_kernel<<<dim3(VD/64, BL/64), blk, 0, stream>>>(x, Wg, xgb,    BL, VD, HS);
  gemm_nt_kernel<<<dim3(1,     BL/64), blk, 0, stream>>>(x, Wb, xbb, BL, NE*NH, HS);
  gemm_nt_kernel<<<dim3(1,     BL/64), blk, 0, stream>>>(x, Wa, xab, BL, NE*NH, HS);
  // conv + silu
  conv_silu_kernel<<<(BL*(KD/4))/256, blk, 0, stream>>>(xq_raw, cq, qb, KD);
  conv_silu_kernel<<<(BL*(KD/4))/256, blk, 0, stream>>>(xk_raw, ck, kb, KD);
  conv_silu_kernel<<<(BL*(VD/4))/256, blk, 0, stream>>>(xv_raw, cv, vb, VD);
  // l2norm (q gets *HD^-0.5)
  l2norm_kernel<<<(BL*NH)/4, blk, 0, stream>>>(qb, 0.0625f, BL*NH);
  l2norm_kernel<<<(BL*NH)/4, blk, 0, stream>>>(kb, 1.0f,    BL*NH);
  // per-expert per-head key transform
  gemm_ke_kernel<<<dim3(HD/64, BL/64, NE*NH), blk, 0, stream>>>(kb, Wek, keb);
  // gate scalars + expert mixing weights
  scalars_kernel<<<(BL*NE*NH + 255)/256, blk, 0, stream>>>(xbb, xab, modv, Alog, dtb, decb, bmb);
  wout_kernel<<<1, 64, 0, stream>>>(ow, woutb);
  // scan (o must be zeroed: experts accumulate atomically)
  hipMemsetAsync(ob, 0, (size_t)BL * VD * sizeof(float), stream);
  scan_kernel<<<NE * Bc * NH * 32, 64, 0, stream>>>(keb, qb, vb, decb, bmb, woutb, ob);
  // RMSNorm * silu(gate)
  gate_kernel<<<(BL*NH)/4, blk, 0, stream>>>(ob, xgb, onw);
  // output projection
  gemm_nt_kernel<<<dim3(HS/64, BL/64), blk, 0, stream>>>(ob, Wo, out, BL, HS, VD);
}

// Round 3
// 2189.510 us; speedup vs baseline: 1.7288x; 1.7288x over previous
//
#include <hip/hip_runtime.h>
#include <math.h>

// ---- problem constants ----
constexpr int Bc  = 2;
constexpr int Lc  = 1024;
constexpr int BL  = Bc * Lc;    // 2048
constexpr int HS  = 2048;
constexpr int NH  = 8;
constexpr int HD  = 256;
constexpr int DV  = 512;
constexpr int KD  = NH * HD;    // 2048
constexpr int VD  = NH * DV;    // 4096
constexpr int NE  = 3;
constexpr int KSZ = 4;
constexpr int NCAT = 12288;     // Wq|Wk|Wv|Wg rows concatenated

__device__ __forceinline__ float sigf(float x) { return 1.f / (1.f + expf(-x)); }

__device__ __forceinline__ ushort f2bf(float f) {
  unsigned u = __float_as_uint(f);
  unsigned r = u + 0x7fffu + ((u >> 16) & 1u);
  return (ushort)(r >> 16);
}
__device__ __forceinline__ float bf2f(ushort u) {
  return __uint_as_float(((unsigned)u) << 16);
}

typedef __attribute__((ext_vector_type(8))) short bf16x8;
typedef __attribute__((ext_vector_type(4))) float f32x4;

#define AS1C(p) ((const __attribute__((address_space(1))) void*)(p))
#define AS3(p)  ((__attribute__((address_space(3))) void*)(p))

// =====================================================================
// fp32 -> bf16 (RNE) elementwise, vectorized x4
// =====================================================================
__global__ __launch_bounds__(256) void cvt_kernel(const float* __restrict__ in,
                                                  ushort* __restrict__ out, int n4) {
  int i = blockIdx.x * blockDim.x + threadIdx.x;
  if (i >= n4) return;
  float4 v = ((const float4*)in)[i];
  ushort4 o;
  o.x = f2bf(v.x); o.y = f2bf(v.y); o.z = f2bf(v.z); o.w = f2bf(v.w);
  ((ushort4*)out)[i] = o;
}

// =====================================================================
// bf16 MFMA GEMM core: C[M,N] = A[M,K] * B[N,K]^T, bf16 inputs row-major,
// fp32 accumulate, output fp32 or bf16. 128x128 tile, BK=32, 4 waves (2x2
// of 64x64), m97 structure: global_load_lds width=16, XOR-swizzled LDS.
// mfma_f32_16x16x32_bf16: A op: m=lane&15, k=8*(lane>>4)+j; B op supplies
// W[n=lane&15, k] giving D = A·W^T; C/D: col=lane&15, row=4*(lane>>4)+reg.
// =====================================================================
template<bool BF16OUT>
__device__ __forceinline__ void mfma_core(const ushort* __restrict__ A, int lda,
                                          const ushort* __restrict__ B, int ldb,
                                          void* __restrict__ Cv, int ldc,
                                          int K, int m0, int n0,
                                          ushort* As, ushort* Bs) {
  const int tid = threadIdx.x;
  const int w = tid >> 6, lane = tid & 63;
  const int wm = (w >> 1) << 6, wn = (w & 1) << 6;
  f32x4 acc[4][4];
#pragma unroll
  for (int i = 0; i < 4; i++)
#pragma unroll
    for (int j = 0; j < 4; j++) acc[i][j] = (f32x4){0.f, 0.f, 0.f, 0.f};

  // staging: wave w loads chunks {2w,2w+1}; chunk = 16 rows x 32 cols (bf16)
  const int rc = lane >> 2;                 // row within chunk 0..15
  const int slot = lane & 3;                // 16B slot within row
  const int r0 = (2 * w) * 16 + rc;
  const int r1 = (2 * w + 1) * 16 + rc;
  const int g0 = slot ^ (r0 & 3);           // XOR swizzle applied on global side
  const int g1 = slot ^ (r1 & 3);
  const ushort* A0 = A + (size_t)(m0 + r0) * lda + g0 * 8;
  const ushort* A1 = A + (size_t)(m0 + r1) * lda + g1 * 8;
  const ushort* B0 = B + (size_t)(n0 + r0) * ldb + g0 * 8;
  const ushort* B1 = B + (size_t)(n0 + r1) * ldb + g1 * 8;
  ushort* lA0 = As + (2 * w) * 512;         // wave-uniform LDS bases
  ushort* lA1 = As + (2 * w + 1) * 512;
  ushort* lB0 = Bs + (2 * w) * 512;
  ushort* lB1 = Bs + (2 * w + 1) * 512;

  const int gi = ((lane >> 4) ^ (lane & 3)) << 3;  // frag k-slot, unswizzled
  const int fr = lane & 15;

  for (int k0 = 0; k0 < K; k0 += 32) {
    __builtin_amdgcn_global_load_lds(AS1C(A0 + k0), AS3(lA0), 16, 0, 0);
    __builtin_amdgcn_global_load_lds(AS1C(A1 + k0), AS3(lA1), 16, 0, 0);
    __builtin_amdgcn_global_load_lds(AS1C(B0 + k0), AS3(lB0), 16, 0, 0);
    __builtin_amdgcn_global_load_lds(AS1C(B1 + k0), AS3(lB1), 16, 0, 0);
    __syncthreads();
    bf16x8 af[4], bff[4];
#pragma unroll
    for (int i = 0; i < 4; i++) {
      af[i]  = *(const bf16x8*)&As[(wm + i * 16 + fr) * 32 + gi];
      bff[i] = *(const bf16x8*)&Bs[(wn + i * 16 + fr) * 32 + gi];
    }
#pragma unroll
    for (int i = 0; i < 4; i++)
#pragma unroll
      for (int j = 0; j < 4; j++)
        acc[i][j] = __builtin_amdgcn_mfma_f32_16x16x32_bf16(af[i], bff[j], acc[i][j], 0, 0, 0);
    __syncthreads();
  }
#pragma unroll
  for (int i = 0; i < 4; i++) {
#pragma unroll
    for (int r = 0; r < 4; r++) {
      int row = m0 + wm + i * 16 + (lane >> 4) * 4 + r;
#pragma unroll
      for (int j = 0; j < 4; j++) {
        int col = n0 + wn + j * 16 + fr;
        float val = acc[i][j][r];
        if (BF16OUT) ((ushort*)Cv)[(size_t)row * ldc + col] = f2bf(val);
        else         ((float*)Cv)[(size_t)row * ldc + col]  = val;
      }
    }
  }
}

__global__ __launch_bounds__(256) void gemm_big_kernel(const ushort* __restrict__ A,
    const ushort* __restrict__ B, ushort* __restrict__ C) {
  __shared__ ushort As[4096], Bs[4096];
  mfma_core<true>(A, HS, B, HS, C, NCAT, HS, blockIdx.y * 128, blockIdx.x * 128, As, Bs);
}

__global__ __launch_bounds__(256) void gemm_wo_kernel(const ushort* __restrict__ A,
    const ushort* __restrict__ B, float* __restrict__ C) {
  __shared__ ushort As[4096], Bs[4096];
  mfma_core<false>(A, VD, B, VD, C, HS, VD, blockIdx.y * 128, blockIdx.x * 128, As, Bs);
}

// ke[e, t, h*HD + c] = sum_d kbf[t, h*HD+d] * wek[e,h,c,d]   (z = e*NH+h)
__global__ __launch_bounds__(256) void gemm_ke_kernel(const ushort* __restrict__ kbf,
    const ushort* __restrict__ wek, float* __restrict__ ke) {
  __shared__ ushort As[4096], Bs[4096];
  int z = blockIdx.z, e = z >> 3, h = z & 7;
  mfma_core<false>(kbf + h * HD, KD, wek + (size_t)z * HD * HD, HD,
                   ke + (size_t)e * BL * KD + h * HD, KD, HD,
                   blockIdx.y * 128, blockIdx.x * 128, As, Bs);
}

// =====================================================================
// fp32 fallback GEMM (small N: Wb/Wa projections), 64x64 tile
// =====================================================================
__device__ __forceinline__ void gemm_body(const float* __restrict__ A, int lda,
                                          const float* __restrict__ W, int ldw,
                                          float* __restrict__ C, int ldc,
                                          int M, int N, int K,
                                          float* As, float* Ws) {
  const int tid = threadIdx.x;
  const int m0 = blockIdx.y * 64, n0 = blockIdx.x * 64;
  const int tx = tid & 15, ty = tid >> 4;
  const int lr = tid >> 2;
  const int lc = (tid & 3) << 2;
  float acc[4][4] = {{0.f,0.f,0.f,0.f},{0.f,0.f,0.f,0.f},{0.f,0.f,0.f,0.f},{0.f,0.f,0.f,0.f}};
  for (int k0 = 0; k0 < K; k0 += 16) {
    float4 av = make_float4(0.f,0.f,0.f,0.f), wv = make_float4(0.f,0.f,0.f,0.f);
    if (m0 + lr < M) av = *(const float4*)&A[(size_t)(m0 + lr) * lda + k0 + lc];
    if (n0 + lr < N) wv = *(const float4*)&W[(size_t)(n0 + lr) * ldw + k0 + lc];
    __syncthreads();
    As[(lc+0)*68 + lr] = av.x; As[(lc+1)*68 + lr] = av.y;
    As[(lc+2)*68 + lr] = av.z; As[(lc+3)*68 + lr] = av.w;
    Ws[(lc+0)*68 + lr] = wv.x; Ws[(lc+1)*68 + lr] = wv.y;
    Ws[(lc+2)*68 + lr] = wv.z; Ws[(lc+3)*68 + lr] = wv.w;
    __syncthreads();
#pragma unroll
    for (int kk = 0; kk < 16; kk++) {
      float4 a4 = *(const float4*)&As[kk*68 + ty*4];
      float4 w4 = *(const float4*)&Ws[kk*68 + tx*4];
      float ar[4] = {a4.x, a4.y, a4.z, a4.w};
      float wr[4] = {w4.x, w4.y, w4.z, w4.w};
#pragma unroll
      for (int i = 0; i < 4; i++)
#pragma unroll
        for (int j = 0; j < 4; j++)
          acc[i][j] = fmaf(ar[i], wr[j], acc[i][j]);
    }
  }
#pragma unroll
  for (int i = 0; i < 4; i++) {
    int m = m0 + ty*4 + i;
    if (m >= M) continue;
#pragma unroll
    for (int j = 0; j < 4; j++) {
      int n = n0 + tx*4 + j;
      if (n < N) C[(size_t)m * ldc + n] = acc[i][j];
    }
  }
}

__global__ __launch_bounds__(256) void gemm_nt_kernel(const float* __restrict__ A,
    const float* __restrict__ W, float* __restrict__ C, int M, int N, int K) {
  __shared__ float As[16*68];
  __shared__ float Ws[16*68];
  gemm_body(A, K, W, K, C, N, M, N, K, As, Ws);
}

// =====================================================================
// causal depthwise conv (K=4) + SiLU. x: bf16 [BL, ldx] strided view.
// y: f32 [BL,C] if obf==0, bf16 [BL,C] if obf==1.
// =====================================================================
__global__ __launch_bounds__(256) void conv_silu_kernel(const ushort* __restrict__ x, int ldx,
    const float* __restrict__ w, void* __restrict__ y, int C, int obf) {
  int idx = blockIdx.x * blockDim.x + threadIdx.x;
  int nc4 = C >> 2;
  if (idx >= BL * nc4) return;
  int c4 = (idx % nc4) << 2;
  int t  = idx / nc4;
  int b = t / Lc, l = t % Lc;
  float4 w0 = *(const float4*)&w[(c4+0)*KSZ];
  float4 w1 = *(const float4*)&w[(c4+1)*KSZ];
  float4 w2 = *(const float4*)&w[(c4+2)*KSZ];
  float4 w3 = *(const float4*)&w[(c4+3)*KSZ];
  const float* p0 = (const float*)&w0; const float* p1 = (const float*)&w1;
  const float* p2 = (const float*)&w2; const float* p3 = (const float*)&w3;
  float4 acc = make_float4(0.f,0.f,0.f,0.f);
#pragma unroll
  for (int i = 0; i < KSZ; i++) {
    int ls = l - (KSZ - 1) + i;
    if (ls < 0) continue;
    ushort4 xu = *(const ushort4*)&x[(size_t)(b * Lc + ls) * ldx + c4];
    acc.x = fmaf(bf2f(xu.x), p0[i], acc.x);
    acc.y = fmaf(bf2f(xu.y), p1[i], acc.y);
    acc.z = fmaf(bf2f(xu.z), p2[i], acc.z);
    acc.w = fmaf(bf2f(xu.w), p3[i], acc.w);
  }
  acc.x *= sigf(acc.x); acc.y *= sigf(acc.y); acc.z *= sigf(acc.z); acc.w *= sigf(acc.w);
  if (obf) {
    ushort4 o;
    o.x = f2bf(acc.x); o.y = f2bf(acc.y); o.z = f2bf(acc.z); o.w = f2bf(acc.w);
    *(ushort4*)&((ushort*)y)[(size_t)t * C + c4] = o;
  } else {
    *(float4*)&((float*)y)[(size_t)t * C + c4] = acc;
  }
}

// =====================================================================
// l2norm over last dim (HD=256) in place, one wave per row, * scale
// =====================================================================
__global__ __launch_bounds__(256) void l2norm_kernel(float* __restrict__ q, float scale, int rows) {
  int wid = threadIdx.x >> 6, lane = threadIdx.x & 63;
  int row = (blockIdx.x << 2) + wid;
  if (row >= rows) return;
  float* p = q + (size_t)row * HD;
  float4 a = *(const float4*)&p[lane * 4];
  float ss = a.x*a.x + a.y*a.y + a.z*a.z + a.w*a.w;
#pragma unroll
  for (int off = 32; off >= 1; off >>= 1) ss += __shfl_xor(ss, off, 64);
  float r = rsqrtf(ss + 1e-6f) * scale;
  a.x *= r; a.y *= r; a.z *= r; a.w *= r;
  *(float4*)&p[lane * 4] = a;
}

// =====================================================================
// per-token gate scalars: dec = m*exp(g)+(1-m), bm = beta*m
// =====================================================================
__global__ __launch_bounds__(256) void scalars_kernel(const float* __restrict__ xb,
    const float* __restrict__ xa, const int* __restrict__ modality,
    const float* __restrict__ A_log, const float* __restrict__ dt_bias,
    float* __restrict__ dec, float* __restrict__ bm) {
  int idx = blockIdx.x * blockDim.x + threadIdx.x;
  if (idx >= BL * NE * NH) return;
  int eh = idx % (NE * NH);
  int t  = idx / (NE * NH);
  int e = eh / NH, h = eh % NH;
  float a    = xa[(size_t)t * (NE*NH) + eh];
  float beta = sigf(xb[(size_t)t * (NE*NH) + eh]);
  int md = modality[t];
  float m = (e == 0) ? 1.f : ((e == 1) ? (md == 0 ? 1.f : 0.f) : (md == 1 ? 1.f : 0.f));
  float spin = a + dt_bias[eh];
  float sp = (spin > 20.f) ? spin : log1pf(expf(spin));
  float g = -expf(A_log[eh]) * sp;
  float d = m * expf(g) + (1.f - m);
  int b = t / Lc, l = t % Lc;
  size_t off = ((size_t)(e * Bc + b) * NH + h) * Lc + l;
  dec[off] = d;
  bm[off]  = beta * m;
}

__global__ void wout_kernel(const float* __restrict__ ow, float* __restrict__ wout) {
  int h = threadIdx.x;
  if (h >= NH) return;
  float e0 = ow[0*NH + h], e1 = ow[1*NH + h], e2 = ow[2*NH + h];
  float mx = fmaxf(e0, fmaxf(e1, e2));
  float x0 = expf(e0 - mx), x1 = expf(e1 - mx), x2 = expf(e2 - mx);
  float s = x0 + x1 + x2;
  wout[0*NH + h] = x0 / s; wout[1*NH + h] = x1 / s; wout[2*NH + h] = x2 / s;
}

// =====================================================================
// gated delta scan. One wave per (e, b, h, 8-column chunk of DV).
// lane = p*8 + vl: column vl (of 8), k-slice p (32 k's in regs). No LDS, no
// barriers; same-address lane groups broadcast from L1/L2. Wave-uniform skip
// of the state update when bm==0 && dec==1 (masked expert token: exact no-op).
// v is bf16.
// =====================================================================
__global__ __launch_bounds__(64) void scan_kernel(
    const float* __restrict__ ke, const float* __restrict__ q,
    const ushort* __restrict__ v, const float* __restrict__ dec,
    const float* __restrict__ bm, const float* __restrict__ wout,
    float* __restrict__ o) {
  const int wg = blockIdx.x;
  const int chunk = wg & 63;
  const int h = (wg >> 6) & 7;
  const int b = (wg >> 9) & 1;
  const int e = wg >> 10;
  const int lane = threadIdx.x;
  const int vl = lane & 7, p = lane >> 3;

  float S[32];
#pragma unroll
  for (int i = 0; i < 32; i++) S[i] = 0.f;

  const float* decp = dec + ((size_t)(e * Bc + b) * NH + h) * Lc;
  const float* bmp  = bm  + ((size_t)(e * Bc + b) * NH + h) * Lc;
  const float weh = wout[e * NH + h];
  const float* kp = ke + ((size_t)e * BL + (size_t)b * Lc) * KD + h * HD + p * 32;
  const float* qp = q  + ((size_t)b * Lc) * KD + h * HD + p * 32;
  const ushort* vp = v + ((size_t)b * Lc) * VD + h * DV + chunk * 8 + vl;
  float* ob = o + (size_t)b * Lc * VD + h * DV + chunk * 8;

  for (int t = 0; t < Lc; t++) {
    float4 qr[8];
    const float* qt = qp + (size_t)t * KD;
#pragma unroll
    for (int i = 0; i < 8; i++) qr[i] = *(const float4*)&qt[i * 4];
    const float vval = bf2f(vp[(size_t)t * VD]);
    const float dct = decp[t], bmt = bmp[t];
    float o0 = 0.f, o1 = 0.f, o2 = 0.f, o3 = 0.f;
    if (!(bmt == 0.f && dct == 1.f)) {
      float4 kr[8];
      const float* kt = kp + (size_t)t * KD;
#pragma unroll
      for (int i = 0; i < 8; i++) kr[i] = *(const float4*)&kt[i * 4];
      float pr0 = 0.f, pr1 = 0.f, pr2 = 0.f, pr3 = 0.f;
#pragma unroll
      for (int i = 0; i < 8; i++) {
        pr0 = fmaf(kr[i].x, S[4*i+0], pr0);
        pr1 = fmaf(kr[i].y, S[4*i+1], pr1);
        pr2 = fmaf(kr[i].z, S[4*i+2], pr2);
        pr3 = fmaf(kr[i].w, S[4*i+3], pr3);
      }
      float part = (pr0 + pr1) + (pr2 + pr3);
      part += __shfl_xor(part, 8, 64);
      part += __shfl_xor(part, 16, 64);
      part += __shfl_xor(part, 32, 64);
      const float delta = (vval - dct * part) * bmt;
#pragma unroll
      for (int i = 0; i < 8; i++) {
        float s0 = fmaf(kr[i].x, delta, dct * S[4*i+0]); S[4*i+0] = s0; o0 = fmaf(qr[i].x, s0, o0);
        float s1 = fmaf(kr[i].y, delta, dct * S[4*i+1]); S[4*i+1] = s1; o1 = fmaf(qr[i].y, s1, o1);
        float s2 = fmaf(kr[i].z, delta, dct * S[4*i+2]); S[4*i+2] = s2; o2 = fmaf(qr[i].z, s2, o2);
        float s3 = fmaf(kr[i].w, delta, dct * S[4*i+3]); S[4*i+3] = s3; o3 = fmaf(qr[i].w, s3, o3);
      }
    } else {
#pragma unroll
      for (int i = 0; i < 8; i++) {
        o0 = fmaf(qr[i].x, S[4*i+0], o0);
        o1 = fmaf(qr[i].y, S[4*i+1], o1);
        o2 = fmaf(qr[i].z, S[4*i+2], o2);
        o3 = fmaf(qr[i].w, S[4*i+3], o3);
      }
    }
    float opart = (o0 + o1) + (o2 + o3);
    opart += __shfl_xor(opart, 8, 64);
    opart += __shfl_xor(opart, 16, 64);
    opart += __shfl_xor(opart, 32, 64);
    if (p == 0) atomicAdd(&ob[(size_t)t * VD + vl], weh * opart);
  }
}

// =====================================================================
// RMSNorm(DV) * o_norm_weight * SiLU(gate). gate read (bf16) from xcat.
// =====================================================================
__global__ __launch_bounds__(256) void gate_kernel(float* __restrict__ o,
    const ushort* __restrict__ xg, int ldg, const float* __restrict__ onw) {
  int wid = threadIdx.x >> 6, lane = threadIdx.x & 63;
  int row = (blockIdx.x << 2) + wid;      // over BL*NH
  if (row >= BL * NH) return;
  int t = row >> 3, h = row & 7;
  float* op = o + (size_t)t * VD + h * DV;
  const ushort* gp = xg + (size_t)t * ldg + h * DV;
  float4 a0 = *(const float4*)&op[lane * 8];
  float4 a1 = *(const float4*)&op[lane * 8 + 4];
  float ss = a0.x*a0.x + a0.y*a0.y + a0.z*a0.z + a0.w*a0.w
           + a1.x*a1.x + a1.y*a1.y + a1.z*a1.z + a1.w*a1.w;
#pragma unroll
  for (int off = 32; off >= 1; off >>= 1) ss += __shfl_xor(ss, off, 64);
  float r = rsqrtf(ss * (1.f / DV) + 1e-5f);
  ushort4 gu0 = *(const ushort4*)&gp[lane * 8];
  ushort4 gu1 = *(const ushort4*)&gp[lane * 8 + 4];
  float4 n0 = *(const float4*)&onw[lane * 8];
  float4 n1 = *(const float4*)&onw[lane * 8 + 4];
  float g;
  g = bf2f(gu0.x); a0.x = a0.x * r * n0.x * (g * sigf(g));
  g = bf2f(gu0.y); a0.y = a0.y * r * n0.y * (g * sigf(g));
  g = bf2f(gu0.z); a0.z = a0.z * r * n0.z * (g * sigf(g));
  g = bf2f(gu0.w); a0.w = a0.w * r * n0.w * (g * sigf(g));
  g = bf2f(gu1.x); a1.x = a1.x * r * n1.x * (g * sigf(g));
  g = bf2f(gu1.y); a1.y = a1.y * r * n1.y * (g * sigf(g));
  g = bf2f(gu1.z); a1.z = a1.z * r * n1.z * (g * sigf(g));
  g = bf2f(gu1.w); a1.w = a1.w * r * n1.w * (g * sigf(g));
  *(float4*)&op[lane * 8]     = a0;
  *(float4*)&op[lane * 8 + 4] = a1;
}

// =====================================================================
extern "C" void kernel_launch(void* const* d_in, const int* in_sizes, int n_in,
                              void* d_out, int out_size, void* d_ws, size_t ws_size,
                              hipStream_t stream) {
  const float* x    = (const float*)d_in[0];
  const int*   modv = (const int*)d_in[1];
  const float* Wq   = (const float*)d_in[2];
  const float* Wk   = (const float*)d_in[3];
  const float* Wv   = (const float*)d_in[4];
  const float* cq   = (const float*)d_in[5];
  const float* ck   = (const float*)d_in[6];
  const float* cv   = (const float*)d_in[7];
  const float* Wek  = (const float*)d_in[8];
  const float* Wb   = (const float*)d_in[9];
  const float* Wa   = (const float*)d_in[10];
  const float* Alog = (const float*)d_in[11];
  const float* dtb  = (const float*)d_in[12];
  const float* ow   = (const float*)d_in[13];
  const float* Wg   = (const float*)d_in[14];
  const float* onw  = (const float*)d_in[15];
  const float* Wo   = (const float*)d_in[16];
  float* out = (float*)d_out;

  // ---- workspace layout (total ~197 MB; round-1 proved ws >= ~202 MB) ----
  char* base = (char*)d_ws;
  size_t off = 0;
  auto alloc = [&](size_t bytes) { char* p = base + off; off += (bytes + 255) & ~255ULL; return p; };

  ushort* xcat  = (ushort*)alloc((size_t)BL * NCAT * 2);        // 50.3 MB bf16 q|k|v|g proj
  char*   wkreg = alloc((size_t)NE * BL * KD * 4);              // 50.3 MB: Wcat bf16 -> keb f32
  ushort* wekbf = (ushort*)alloc((size_t)NE * NH * HD * HD * 2);// 3.1 MB
  ushort* xbf   = (ushort*)alloc((size_t)BL * HS * 2);          // 8.4 MB -> kbbf
  float*  qb    = (float*) alloc((size_t)BL * KD * 4);          // 16.8 MB
  char*   kbreg = alloc((size_t)BL * KD * 4);                   // 16.8 MB: kb f32 -> wobf bf16
  char*   vreg  = alloc((size_t)BL * VD * 2);                   // 16.8 MB: v bf16 -> obbf bf16
  float*  ob    = (float*) alloc((size_t)BL * VD * 4);          // 33.6 MB
  float*  xbb   = (float*) alloc((size_t)BL * NE * NH * 4);
  float*  xab   = (float*) alloc((size_t)BL * NE * NH * 4);
  float*  decb  = (float*) alloc((size_t)NE * BL * NH * 4);
  float*  bmb   = (float*) alloc((size_t)NE * BL * NH * 4);
  float*  woutb = (float*) alloc(NE * NH * 4);

  ushort* Wcat = (ushort*)wkreg;          // phase A
  float*  keb  = (float*)wkreg;           // phase C/D (after gemm_big done)
  ushort* kbbf = xbf;                     // after gemm_big done
  float*  kb   = (float*)kbreg;           // phase B/C
  ushort* wobf = (ushort*)kbreg;          // after kb -> kbbf cvt
  ushort* vbf  = (ushort*)vreg;           // phase B..D
  ushort* obbf = (ushort*)vreg;           // after scan

  dim3 blk(256);
  // ---- bf16 conversions (x + weights) ----
  cvt_kernel<<<4096, blk, 0, stream>>>(x,  xbf, BL * HS / 4);
  cvt_kernel<<<4096, blk, 0, stream>>>(Wq, Wcat,                   KD * HS / 4);
  cvt_kernel<<<4096, blk, 0, stream>>>(Wk, Wcat + (size_t)KD*HS,   KD * HS / 4);
  cvt_kernel<<<8192, blk, 0, stream>>>(Wv, Wcat + (size_t)2*KD*HS, VD * HS / 4);
  cvt_kernel<<<8192, blk, 0, stream>>>(Wg, Wcat + (size_t)2*KD*HS + (size_t)VD*HS, VD * HS / 4);
  cvt_kernel<<<1536, blk, 0, stream>>>(Wek, wekbf, NE * NH * HD * HD / 4);
  // ---- fused q|k|v|g projection (bf16 MFMA, bf16 out) ----
  gemm_big_kernel<<<dim3(NCAT/128, BL/128), blk, 0, stream>>>(xbf, Wcat, xcat);
  // ---- small fp32 projections for gates ----
  gemm_nt_kernel<<<dim3(1, BL/64), blk, 0, stream>>>(x, Wb, xbb, BL, NE*NH, HS);
  gemm_nt_kernel<<<dim3(1, BL/64), blk, 0, stream>>>(x, Wa, xab, BL, NE*NH, HS);
  // ---- conv + silu (reads strided bf16 xcat) ----
  conv_silu_kernel<<<4096, blk, 0, stream>>>(xcat,        NCAT, cq, qb, KD, 0);
  conv_silu_kernel<<<4096, blk, 0, stream>>>(xcat + KD,   NCAT, ck, kb, KD, 0);
  conv_silu_kernel<<<8192, blk, 0, stream>>>(xcat + 2*KD, NCAT, cv, vbf, VD, 1);
  // ---- l2norm (q gets *HD^-0.5) ----
  l2norm_kernel<<<(BL*NH)/4, blk, 0, stream>>>(qb, 0.0625f, BL*NH);
  l2norm_kernel<<<(BL*NH)/4, blk, 0, stream>>>(kb, 1.0f,    BL*NH);
  // ---- kb -> bf16, then Wo -> bf16 into kb's region ----
  cvt_kernel<<<4096, blk, 0, stream>>>(kb, kbbf, BL * KD / 4);
  cvt_kernel<<<8192, blk, 0, stream>>>(Wo, wobf, HS * VD / 4);
  // ---- per-expert per-head key transform (bf16 MFMA, f32 out into Wcat region) ----
  gemm_ke_kernel<<<dim3(HD/128, BL/128, NE*NH), blk, 0, stream>>>(kbbf, wekbf, keb);
  // ---- gate scalars + expert mixing ----
  scalars_kernel<<<(BL*NE*NH + 255)/256, blk, 0, stream>>>(xbb, xab, modv, Alog, dtb, decb, bmb);
  wout_kernel<<<1, 64, 0, stream>>>(ow, woutb);
  // ---- scan ----
  hipMemsetAsync(ob, 0, (size_t)BL * VD * sizeof(float), stream);
  scan_kernel<<<NE * Bc * NH * 64, 64, 0, stream>>>(keb, qb, vbf, decb, bmb, woutb, ob);
  // ---- RMSNorm * silu(gate) ----
  gate_kernel<<<(BL*NH)/4, blk, 0, stream>>>(ob, xcat + 2*KD + VD, NCAT, onw);
  // ---- output projection (bf16 MFMA) ----
  cvt_kernel<<<8192, blk, 0, stream>>>(ob, obbf, BL * VD / 4);
  gemm_wo_kernel<<<dim3(HS/128, BL/128), blk, 0, stream>>>(obbf, wobf, out);
}